// Round 7
// baseline (4062.222 us; speedup 1.0000x reference)
//
#include <hip/hip_runtime.h>
#include <hip/hip_bf16.h>

#define BB 256
#define LINES 64
#define NREG 64
#define DD 1024
#define FF 1024

constexpr float EPS = 1e-5f;
constexpr float SCALE = 0.03125f; // 1/sqrt(1024)

typedef __bf16 bf16_t;
typedef bf16_t bf16x8 __attribute__((ext_vector_type(8)));
typedef unsigned short us16x8 __attribute__((ext_vector_type(8)));
typedef float f32x4 __attribute__((ext_vector_type(4)));
typedef unsigned u32x4v __attribute__((ext_vector_type(4)));
typedef unsigned long long u64;

// ---------------- d_ws layout (bytes) ----------------
#define WS_W1T   0u                         // w1^T  [f][d] bf16, 2MB
#define WS_W2T   (2u << 20)                 // w2^T  [f][d] bf16, 2MB
#define WS_WRT   (4u << 20)                 // w_res^T [d][f] bf16, 2MB
#define WS_XNP   (6u << 20)                 // xnp [16g][16j][1024] u32 (bf16 xn0|xn1), 1MB
#define WS_MIXP  (7u << 20)                 // mixp [16g][16][1024] bf16, 512KB
#define WS_GT    ((7u << 20) + (1u << 19))  // gt  [16g][16][1024] f32, 1MB
#define WS_CTR   ((8u << 20) + (1u << 19))  // 16 groups x 64B flag line
#define WS_NEED  (WS_CTR + 1024u)

// ---------------- LDS layout (bytes) ----------------
#define SM_WV    0
#define SM_AT0P  256
#define SM_AT1P  512
#define SM_SC0   768
#define SM_SC1   1024
#define SM_SCW   1280
#define SM_RED   1536
#define SM_DYN   2048
#define SM_OSB   SM_DYN                     // [16][1088] f32 (aliases AT0/AT1; disjoint in time)
#define SM_AT0   SM_DYN                     // 32KB bf16 [16][1024] XOR-swizzled (xn0 / mix tile)
#define SM_AT1   (SM_DYN + 32768)           // 32KB tile for xn1
#define SM_RED2  (SM_DYN + 65536)           // [3][4][16][17] f32 = 13056B
#define SM_PRE   (SM_DYN + 65536 + 13056)   // [2][16][66] f32 = 8448B
#define SM_VAL   (SM_DYN + 65536 + 13056 + 8448)  // [64*17] f32 padded = 4352B
#define SM_QPF   (SM_VAL + 4352)            // 3 x [64*20] f32 padded = 15360B (q0,q1,kw prefetch)
#define SM_SIZE  (SM_QPF + 15360)

__device__ __forceinline__ float wred(float v) {
#pragma unroll
  for (int m = 32; m >= 1; m >>= 1) v += __shfl_xor(v, m);
  return v;
}
__device__ __forceinline__ float wmax64(float v) {
#pragma unroll
  for (int m = 32; m >= 1; m >>= 1) v = fmaxf(v, __shfl_xor(v, m));
  return v;
}

// ---- LLC-coherent (sc0 sc1) access helpers: bypass L1 and non-coherent XCD L2 ----
__device__ __forceinline__ void st_llc32(void* p, unsigned v) {
  asm volatile("global_store_dword %0, %1, off sc0 sc1" :: "v"(p), "v"(v) : "memory");
}
__device__ __forceinline__ void st_llc16b(void* p, unsigned short v) {
  unsigned vv = v;
  asm volatile("global_store_short %0, %1, off sc0 sc1" :: "v"(p), "v"(vv) : "memory");
}
__device__ __forceinline__ unsigned ld_llc32(const void* p) {
  unsigned r;
  asm volatile("global_load_dword %0, %1, off sc0 sc1\n\ts_waitcnt vmcnt(0)"
               : "=v"(r) : "v"(p) : "memory");
  return r;
}
// no-wait variants: caller must execute wait_vm0() before use
__device__ __forceinline__ void ld_llc_4x8_nw(const void* p, u64& a, u64& b, u64& c, u64& d) {
  asm volatile(
      "global_load_dwordx2 %0, %4, off sc0 sc1\n\t"
      "global_load_dwordx2 %1, %4, off offset:8 sc0 sc1\n\t"
      "global_load_dwordx2 %2, %4, off offset:16 sc0 sc1\n\t"
      "global_load_dwordx2 %3, %4, off offset:24 sc0 sc1"
      : "=&v"(a), "=&v"(b), "=&v"(c), "=&v"(d) : "v"(p) : "memory");
}
__device__ __forceinline__ void ld_llc_16_nw(const void* p, u32x4v& r) {
  asm volatile("global_load_dwordx4 %0, %1, off sc0 sc1"
               : "=&v"(r) : "v"(p) : "memory");
}
__device__ __forceinline__ void wait_vm0() {
  asm volatile("s_waitcnt vmcnt(0)" ::: "memory");
  __builtin_amdgcn_sched_barrier(0);   // rule #18: keep dependent ops below the wait
}

// Flag-based fence-free group barrier (replaces atomic-counter version):
// producer path: drain vmcnt (data stores at LLC) -> syncthreads -> tid0
// STORES monotonically-increasing tag to its own dword of the group's 64B
// flag line (no RMW, no serialization). Wave 0's lanes 0-15 poll all 16
// flags (one coalesced 64B LLC read per poll) until all >= tag.
__device__ __forceinline__ void group_barrier(unsigned* flg, int tid, int m, unsigned tag) {
  asm volatile("s_waitcnt vmcnt(0)" ::: "memory");
  __syncthreads();
  if (tid < 64) {
    if (tid == 0) st_llc32(&flg[m], tag);
    for (;;) {
      unsigned v = (tid < 16) ? ld_llc32(&flg[tid]) : tag;
      if (__all(v >= tag)) break;
      __builtin_amdgcn_s_sleep(2);
    }
  }
  __syncthreads();
}

// transpose + f32->bf16: dst[j][i] = src[i][j], 1024x1024; z selects matrix
__global__ __launch_bounds__(256) void transcvt(const float* __restrict__ w1,
                                                const float* __restrict__ w2,
                                                const float* __restrict__ wr,
                                                bf16_t* __restrict__ out) {
  __shared__ float tl[64][65];
  const float* src = (blockIdx.z == 0) ? w1 : (blockIdx.z == 1) ? w2 : wr;
  bf16_t* dst = out + (size_t)blockIdx.z * (1u << 20);
  const int i0 = blockIdx.x * 64, j0 = blockIdx.y * 64;
  const int t = threadIdx.x;
#pragma unroll
  for (int it = 0; it < 4; ++it) {
    int r = (t >> 4) + it * 16;
    int c4 = (t & 15) * 4;
    const float4 v = *reinterpret_cast<const float4*>(&src[(size_t)(i0 + r) * 1024 + j0 + c4]);
    tl[r][c4] = v.x; tl[r][c4 + 1] = v.y; tl[r][c4 + 2] = v.z; tl[r][c4 + 3] = v.w;
  }
  __syncthreads();
  const int orow = t >> 2, seg = t & 3;
  bf16x8 v0, v1;
#pragma unroll
  for (int u = 0; u < 8; ++u) {
    v0[u] = (bf16_t)tl[seg * 16 + u][orow];
    v1[u] = (bf16_t)tl[seg * 16 + 8 + u][orow];
  }
  bf16_t* dp = dst + (size_t)(j0 + orow) * 1024 + i0 + seg * 16;
  *reinterpret_cast<bf16x8*>(dp) = v0;
  *reinterpret_cast<bf16x8*>(dp + 8) = v1;
}

__global__ __launch_bounds__(1024, 4) void interp3(
    const float* __restrict__ opcode_probs, const float* __restrict__ Rin,
    const float* __restrict__ k_write, const float* __restrict__ q_read,
    const float* __restrict__ gate,
    const float* __restrict__ ln1_g, const float* __restrict__ ln1_b, const float* __restrict__ b1,
    const float* __restrict__ ln2_g, const float* __restrict__ ln2_b, const float* __restrict__ b2,
    const float* __restrict__ b_res, const float* __restrict__ lno_g, const float* __restrict__ lno_b,
    char* __restrict__ ws, float* __restrict__ Rout) {
  __shared__ __align__(16) char smem[SM_SIZE];
  float* wvp  = (float*)(smem + SM_WV);
  float* at0p = (float*)(smem + SM_AT0P);
  float* at1p = (float*)(smem + SM_AT1P);
  float* sc0p = (float*)(smem + SM_SC0);
  float* sc1p = (float*)(smem + SM_SC1);
  float* scwp = (float*)(smem + SM_SCW);
  float* redp = (float*)(smem + SM_RED);

  const int b = blockIdx.x;
  // STRIDE-16 group topology (probe of chunked block->XCD dispatch):
  // group g = blocks {b : b&15 == g}; member/slice/row index m = j = b>>4.
  // Under 32-chunked dispatch each XCD sees only 2 slices (768KB weights).
  const int g = b & 15;
  const int j = b >> 4;
  const int m = j;
  const int bq = b;
  const int tid = threadIdx.x;
  const int w = tid >> 6, lane = tid & 63;
  const int ln15 = lane & 15, kgrp = lane >> 4;

  const bf16_t* w1t = (const bf16_t*)(ws + WS_W1T);
  const bf16_t* w2t = (const bf16_t*)(ws + WS_W2T);
  const bf16_t* wrt = (const bf16_t*)(ws + WS_WRT);
  unsigned* xnp   = (unsigned*)(ws + WS_XNP);   // packed (bf16 xn0 | bf16 xn1)
  bf16_t*  mixp   = (bf16_t*)(ws + WS_MIXP);
  unsigned* gtw   = (unsigned*)(ws + WS_GT);    // f32 bits
  unsigned* flg   = (unsigned*)(ws + WS_CTR) + g * 16;

  // R rows [4w, 4w+4), columns [16*lane, 16*lane+16) live in registers.
  float Rr_[4][16];
  {
    const float* Rsrc = Rin + (size_t)bq * (NREG * DD);
#pragma unroll
    for (int rr = 0; rr < 4; ++rr) {
#pragma unroll
      for (int c = 0; c < 4; ++c) {
        float4 v = *(const float4*)(Rsrc + (size_t)(4 * w + rr) * DD + lane * 16 + c * 4);
        Rr_[rr][c * 4 + 0] = v.x; Rr_[rr][c * 4 + 1] = v.y;
        Rr_[rr][c * 4 + 2] = v.z; Rr_[rr][c * 4 + 3] = v.w;
      }
    }
  }

  // Prologue: stage step-0 q0/q1/kw into padded LDS prefetch buffers.
  {
    const float* qb = q_read + ((size_t)bq * LINES + 0) * (2 * DD);
    const float* kb = k_write + ((size_t)bq * LINES + 0) * DD;
    float* qpf = (float*)(smem + SM_QPF);
    const int pidx = (tid >> 4) * 20 + (tid & 15);
    qpf[pidx] = qb[tid];
    qpf[1280 + pidx] = qb[DD + tid];
    qpf[2560 + pidx] = kb[tid];
  }
  __syncthreads();

  unsigned nbar = 0;

  for (int t = 0; t < LINES; ++t) {
    // ---- Phase A: attention scores from register-resident R; q from LDS ----
    {
      const float* qpf = (const float*)(smem + SM_QPF);
      const int pb = lane * 20;
#pragma unroll
      for (int v = 0; v < 3; ++v) {
        float* dst = (v == 0) ? sc0p : (v == 1) ? sc1p : scwp;
        float qv[16];
#pragma unroll
        for (int c = 0; c < 4; ++c) {
          float4 t4 = *(const float4*)(qpf + v * 1280 + pb + c * 4);
          qv[c * 4 + 0] = t4.x; qv[c * 4 + 1] = t4.y;
          qv[c * 4 + 2] = t4.z; qv[c * 4 + 3] = t4.w;
        }
#pragma unroll
        for (int rr = 0; rr < 4; ++rr) {
          float s = 0.f;
#pragma unroll
          for (int jj = 0; jj < 16; ++jj) s = fmaf(Rr_[rr][jj], qv[jj], s);
          s = wred(s);
          if (lane == 0) dst[4 * w + rr] = s * SCALE;
        }
      }
    }
    __syncthreads();
    // ---- Phase B: three 64-wide softmaxes ----
    if (w < 3) {
      const float* src = (w == 0) ? sc0p : (w == 1) ? sc1p : scwp;
      float* dst = (w == 0) ? at0p : (w == 1) ? at1p : wvp;
      float v = src[lane];
      float mx = wmax64(v);
      float e = expf(v - mx);
      float s = wred(e);
      dst[lane] = e / s;
    }
    // prefetch next step's q0/q1/kw early (plain cached loads; used in Phase I)
    float pf0, pf1, pf2;
    {
      int tn = (t + 1 < LINES) ? (t + 1) : (LINES - 1);
      const float* qb2 = q_read + ((size_t)bq * LINES + tn) * (2 * DD);
      const float* kb2 = k_write + ((size_t)bq * LINES + tn) * DD;
      pf0 = qb2[tid]; pf1 = qb2[DD + tid]; pf2 = kb2[tid];
    }
    __syncthreads();
    // ---- Phase C: op_s via register FMAs + padded-LDS cross-wave reduce ----
    float os0, os1;
    {
      float p0[16], p1[16];
#pragma unroll
      for (int jj = 0; jj < 16; ++jj) { p0[jj] = 0.f; p1[jj] = 0.f; }
#pragma unroll
      for (int rr = 0; rr < 4; ++rr) {
        float a0 = at0p[4 * w + rr], a1 = at1p[4 * w + rr];
#pragma unroll
        for (int jj = 0; jj < 16; ++jj) {
          p0[jj] = fmaf(a0, Rr_[rr][jj], p0[jj]);
          p1[jj] = fmaf(a1, Rr_[rr][jj], p1[jj]);
        }
      }
      float* osb = (float*)(smem + SM_OSB);
      const int rp = (tid >> 4) * 17 + (tid & 15);
#pragma unroll
      for (int jj = 0; jj < 16; ++jj) osb[w * 1088 + lane * 17 + jj] = p0[jj];
      __syncthreads();
      os0 = 0.f;
#pragma unroll
      for (int ww = 0; ww < 16; ++ww) os0 += osb[ww * 1088 + rp];
      __syncthreads();
#pragma unroll
      for (int jj = 0; jj < 16; ++jj) osb[w * 1088 + lane * 17 + jj] = p1[jj];
      __syncthreads();
      os1 = 0.f;
#pragma unroll
      for (int ww = 0; ww < 16; ++ww) os1 += osb[ww * 1088 + rp];
    }
    // ---- Phase D: LN1/LN2 -> xnp row j (packed bf16 pair, LLC store) ----
    {
      float s0 = wred(os0), qq0 = wred(os0 * os0);
      float s1 = wred(os1), qq1 = wred(os1 * os1);
      if (lane == 0) { redp[w*4] = s0; redp[w*4+1] = qq0; redp[w*4+2] = s1; redp[w*4+3] = qq1; }
      __syncthreads();
      float S0 = 0, Q0 = 0, S1 = 0, Q1 = 0;
#pragma unroll
      for (int i = 0; i < 16; ++i) { S0 += redp[i*4]; Q0 += redp[i*4+1]; S1 += redp[i*4+2]; Q1 += redp[i*4+3]; }
      float m0 = S0 * (1.f / DD), v0 = fmaxf(Q0 * (1.f / DD) - m0 * m0, 0.f);
      float m1 = S1 * (1.f / DD), v1 = fmaxf(Q1 * (1.f / DD) - m1 * m1, 0.f);
      float xn0v = (os0 - m0) * rsqrtf(v0 + EPS) * ln1_g[tid] + ln1_b[tid];
      float xn1v = (os1 - m1) * rsqrtf(v1 + EPS) * ln2_g[tid] + ln2_b[tid];
      unsigned pw = (unsigned)__builtin_bit_cast(unsigned short, (bf16_t)xn0v)
                  | ((unsigned)__builtin_bit_cast(unsigned short, (bf16_t)xn1v) << 16);
      st_llc32(&xnp[((size_t)g * 16 + j) * DD + tid], pw);
    }
    group_barrier(flg, tid, m, ++nbar);   // bar_A: xnp ready

    // ---- Stage BOTH A-tiles (xn0 -> AT0, xn1 -> AT1), batched loads ----
    {
      const char* base = (const char*)(xnp + (size_t)g * (16 * DD));
      const int row = tid >> 7, k16 = tid & 127;  // rows 0-7; +8 for second half
      u64 a0, a1, a2, a3, c0, c1, c2, c3;
      ld_llc_4x8_nw(base + (size_t)row * 4096 + k16 * 32, a0, a1, a2, a3);
      ld_llc_4x8_nw(base + (size_t)(row + 8) * 4096 + k16 * 32, c0, c1, c2, c3);
      wait_vm0();
#pragma unroll
      for (int h = 0; h < 2; ++h) {
        u64 x0 = h ? c0 : a0, x1 = h ? c1 : a1, x2 = h ? c2 : a2, x3 = h ? c3 : a3;
        int r = row + h * 8;
        us16x8 v0, v1;
        v0[0] = (unsigned short)x0;         v1[0] = (unsigned short)(x0 >> 16);
        v0[1] = (unsigned short)(x0 >> 32); v1[1] = (unsigned short)(x0 >> 48);
        v0[2] = (unsigned short)x1;         v1[2] = (unsigned short)(x1 >> 16);
        v0[3] = (unsigned short)(x1 >> 32); v1[3] = (unsigned short)(x1 >> 48);
        v0[4] = (unsigned short)x2;         v1[4] = (unsigned short)(x2 >> 16);
        v0[5] = (unsigned short)(x2 >> 32); v1[5] = (unsigned short)(x2 >> 48);
        v0[6] = (unsigned short)x3;         v1[6] = (unsigned short)(x3 >> 16);
        v0[7] = (unsigned short)(x3 >> 32); v1[7] = (unsigned short)(x3 >> 48);
        unsigned byte = (unsigned)(r * 2048 + k16 * 16) ^ ((unsigned)(r & 7) << 4);
        *(us16x8*)(smem + SM_AT0 + byte) = v0;
        *(us16x8*)(smem + SM_AT1 + byte) = v1;
      }
    }
    __syncthreads();

    // ---- Phase E: two 16x1024 @ 1024x64 MFMA GEMMs (f-slice m of this block) ----
#pragma unroll
    for (int gm = 0; gm < 2; ++gm) {
      const char* atile = smem + (gm ? SM_AT1 : SM_AT0);
      const int ns = w & 3, ks = w >> 2;          // 4 n-subtiles x 4 k-splits
      const bf16_t* bsrc = (gm ? w2t : w1t) + (size_t)(64 * m + ns * 16 + ln15) * DD;
      f32x4 acc = {0.f, 0.f, 0.f, 0.f};
#pragma unroll
      for (int kc = 0; kc < 8; ++kc) {
        int kb = ks * 256 + kc * 32 + kgrp * 8;
        unsigned abyte = ((unsigned)(ln15 * 2048 + kb * 2)) ^ ((unsigned)(ln15 & 7) << 4);
        bf16x8 av = *(const bf16x8*)(atile + abyte);
        bf16x8 bv = *(const bf16x8*)(bsrc + kb);
        acc = __builtin_amdgcn_mfma_f32_16x16x32_bf16(av, bv, acc, 0, 0, 0);
      }
      float* red2 = (float*)(smem + SM_RED2);
      if (ks > 0) {   // red2 region disjoint from A-tiles: no sync needed before
#pragma unroll
        for (int r2 = 0; r2 < 4; ++r2)
          red2[((ks - 1) * 4 + ns) * (16 * 17) + (kgrp * 4 + r2) * 17 + ln15] = acc[r2];
      }
      __syncthreads();
      if (ks == 0) {
        float* prep = (float*)(smem + SM_PRE) + gm * (16 * 66);
#pragma unroll
        for (int r2 = 0; r2 < 4; ++r2) {
          int crow = kgrp * 4 + r2;
          float v = acc[r2];
#pragma unroll
          for (int kk = 0; kk < 3; ++kk)
            v += red2[(kk * 4 + ns) * (16 * 17) + crow * 17 + ln15];
          prep[crow * 66 + ns * 16 + ln15] = v;
        }
      }
      __syncthreads();
    }
    // ---- Phase F: per-16 softmax + modular digit conv; wave w = batch-row w ----
    {
      float* prep = (float*)(smem + SM_PRE);
      const int bb2 = w, c = lane;
      float xp = prep[bb2 * 66 + c] + b1[64 * m + c];
      float yp = prep[16 * 66 + bb2 * 66 + c] + b2[64 * m + c];
      float mx1 = xp, mx2 = yp;
#pragma unroll
      for (int msk = 1; msk < 16; msk <<= 1) {
        mx1 = fmaxf(mx1, __shfl_xor(mx1, msk));
        mx2 = fmaxf(mx2, __shfl_xor(mx2, msk));
      }
      float e1 = expf(xp - mx1), e2 = expf(yp - mx2);
      float s1 = e1, s2 = e2;
#pragma unroll
      for (int msk = 1; msk < 16; msk <<= 1) {
        s1 += __shfl_xor(s1, msk);
        s2 += __shfl_xor(s2, msk);
      }
      float x = e1 / s1, y = e2 / s2;
      int mm = lane & 15, basel = lane & ~15;
      float addv = 0.f, subv = 0.f;
#pragma unroll
      for (int i = 0; i < 16; ++i) {
        float xi = __shfl(x, basel + i);
        float ya = __shfl(y, basel + ((mm - i) & 15));
        float ys = __shfl(y, basel + ((i - mm) & 15));
        addv = fmaf(xi, ya, addv);
        subv = fmaf(xi, ys, subv);
      }
      // batch for row bb2 of group g under stride-16 topology: (bb2<<4)|g
      int q2 = (bb2 << 4) | g;
      const float* pr = opcode_probs + ((size_t)q2 * LINES + t) * 2;
      float mix = pr[0] * addv + pr[1] * subv;
      st_llc16b(&mixp[((size_t)g * 16 + bb2) * DD + 64 * m + c],
                __builtin_bit_cast(unsigned short, (bf16_t)mix));
    }
    group_barrier(flg, tid, m, ++nbar);   // bar_B: mixp ready

    // ---- Phase G: mix(16x1024) @ w_res(1024x1024), d-slice m of this block ----
    {
      const char* base = (const char*)(mixp + (size_t)g * (16 * DD));
      const int row = tid >> 7, k16 = tid & 127;
      u32x4v va, vb;
      ld_llc_16_nw(base + (size_t)row * 2048 + k16 * 16, va);
      ld_llc_16_nw(base + (size_t)(row + 8) * 2048 + k16 * 16, vb);
      wait_vm0();
      unsigned byte0 = (unsigned)(row * 2048 + k16 * 16) ^ ((unsigned)(row & 7) << 4);
      unsigned byte1 = (unsigned)((row + 8) * 2048 + k16 * 16) ^ ((unsigned)(row & 7) << 4);
      *(u32x4v*)(smem + SM_AT0 + byte0) = va;
      *(u32x4v*)(smem + SM_AT0 + byte1) = vb;
      __syncthreads();
      const int ns = w & 3, ks = w >> 2;
      const bf16_t* bsrc = wrt + (size_t)(64 * m + ns * 16 + ln15) * DD;
      f32x4 acc = {0.f, 0.f, 0.f, 0.f};
#pragma unroll
      for (int kc = 0; kc < 8; ++kc) {
        int kb = ks * 256 + kc * 32 + kgrp * 8;
        unsigned abyte = ((unsigned)(ln15 * 2048 + kb * 2)) ^ ((unsigned)(ln15 & 7) << 4);
        bf16x8 av = *(const bf16x8*)(smem + SM_AT0 + abyte);
        bf16x8 bv = *(const bf16x8*)(bsrc + kb);
        acc = __builtin_amdgcn_mfma_f32_16x16x32_bf16(av, bv, acc, 0, 0, 0);
      }
      float* red2 = (float*)(smem + SM_RED2);
      if (ks > 0) {
#pragma unroll
        for (int r2 = 0; r2 < 4; ++r2)
          red2[((ks - 1) * 4 + ns) * (16 * 17) + (kgrp * 4 + r2) * 17 + ln15] = acc[r2];
      }
      __syncthreads();
      if (ks == 0) {
        int f = 64 * m + ns * 16 + ln15;
#pragma unroll
        for (int r2 = 0; r2 < 4; ++r2) {
          int crow = kgrp * 4 + r2;
          float v = acc[r2];
#pragma unroll
          for (int kk = 0; kk < 3; ++kk)
            v += red2[(kk * 4 + ns) * (16 * 17) + crow * 17 + ln15];
          st_llc32(&gtw[((size_t)g * 16 + crow) * DD + f],
                   __builtin_bit_cast(unsigned, v + b_res[f]));
        }
      }
    }
    group_barrier(flg, tid, m, ++nbar);   // bar_C: gt ready

    // ---- Phase H: output LN on own batch row j ----
    {
      float xv = __builtin_bit_cast(float, ld_llc32(&gtw[((size_t)g * 16 + j) * DD + tid]));
      float s1 = wred(xv), s2 = wred(xv * xv);
      if (lane == 0) { redp[w * 2] = s1; redp[w * 2 + 1] = s2; }
      __syncthreads();
      float S = 0.f, Q = 0.f;
#pragma unroll
      for (int i = 0; i < 16; ++i) { S += redp[i * 2]; Q += redp[i * 2 + 1]; }
      float mn = S * (1.f / DD), vr = fmaxf(Q * (1.f / DD) - mn * mn, 0.f);
      float vv = (xv - mn) * rsqrtf(vr + EPS) * lno_g[tid] + lno_b[tid];
      float* valp = (float*)(smem + SM_VAL);
      valp[(tid >> 4) * 17 + (tid & 15)] = vv;   // padded: conflict-free redistribution
    }
    __syncthreads();
    // ---- Phase I: gated write-back (pure registers) + qpf stage for t+1 ----
    {
      float gtv = gate[(size_t)bq * LINES + t];
      const float* valp = (const float*)(smem + SM_VAL);
      float vvj[16];
#pragma unroll
      for (int jj = 0; jj < 16; ++jj) vvj[jj] = valp[lane * 17 + jj];
#pragma unroll
      for (int rr = 0; rr < 4; ++rr) {
        float gg = gtv * wvp[4 * w + rr];
#pragma unroll
        for (int jj = 0; jj < 16; ++jj)
          Rr_[rr][jj] = Rr_[rr][jj] * (1.f - gg) + gg * vvj[jj];
      }
      float* qpf = (float*)(smem + SM_QPF);
      const int pidx = (tid >> 4) * 20 + (tid & 15);
      qpf[pidx] = pf0;
      qpf[1280 + pidx] = pf1;
      qpf[2560 + pidx] = pf2;
    }
    __syncthreads();   // qpf visible for next iteration's Phase A
  }

  // ---- Final: write register-resident R to output (f32, coalesced) ----
  {
    float* Rdst = Rout + (size_t)bq * (NREG * DD);
#pragma unroll
    for (int rr = 0; rr < 4; ++rr) {
#pragma unroll
      for (int c = 0; c < 4; ++c) {
        float4 v;
        v.x = Rr_[rr][c * 4 + 0]; v.y = Rr_[rr][c * 4 + 1];
        v.z = Rr_[rr][c * 4 + 2]; v.w = Rr_[rr][c * 4 + 3];
        *(float4*)(Rdst + (size_t)(4 * w + rr) * DD + lane * 16 + c * 4) = v;
      }
    }
  }
}

// ---------------- fallback (round-1 structure, f32 weights) ----------------
__global__ __launch_bounds__(1024) void interp_fb(
    const float* __restrict__ opcode_probs, const float* __restrict__ k_write,
    const float* __restrict__ q_read, const float* __restrict__ gate,
    const float* __restrict__ ln1_g, const float* __restrict__ ln1_b,
    const float* __restrict__ w1, const float* __restrict__ b1,
    const float* __restrict__ ln2_g, const float* __restrict__ ln2_b,
    const float* __restrict__ w2, const float* __restrict__ b2,
    const float* __restrict__ w_res, const float* __restrict__ b_res,
    const float* __restrict__ lno_g, const float* __restrict__ lno_b,
    float* __restrict__ R) {
  __shared__ float q0s[DD], q1s[DD], kws[DD];
  __shared__ float sc0[NREG], sc1[NREG], scw[NREG];
  __shared__ float at0[NREG], at1[NREG], wv[NREG];
  __shared__ float xn0[DD], xn1[DD];
  __shared__ float mixs[FF];
  __shared__ float val[DD];
  __shared__ float red[64];
  const int b = blockIdx.x;
  const int tid = threadIdx.x;
  const int w = tid >> 6, lane = tid & 63;
  float* Rb = R + (size_t)b * NREG * DD;
  for (int t = 0; t < LINES; ++t) {
    const float* qb = q_read + ((size_t)b * LINES + t) * 2 * DD;
    const float* kb = k_write + ((size_t)b * LINES + t) * DD;
    q0s[tid] = qb[tid]; q1s[tid] = qb[DD + tid]; kws[tid] = kb[tid];
    __syncthreads();
#pragma unroll
    for (int rr = 0; rr < 4; ++rr) {
      int r = w * 4 + rr;
      const float* Rr = Rb + (size_t)r * DD;
      float a0 = 0.f, a1 = 0.f, aw = 0.f;
#pragma unroll
      for (int jj = 0; jj < 16; ++jj) {
        int d = jj * 64 + lane;
        float rv = Rr[d];
        a0 += rv * q0s[d]; a1 += rv * q1s[d]; aw += rv * kws[d];
      }
      a0 = wred(a0); a1 = wred(a1); aw = wred(aw);
      if (lane == 0) { sc0[r] = a0 * SCALE; sc1[r] = a1 * SCALE; scw[r] = aw * SCALE; }
    }
    __syncthreads();
    if (w < 3) {
      const float* src = (w == 0) ? sc0 : (w == 1) ? sc1 : scw;
      float* dst = (w == 0) ? at0 : (w == 1) ? at1 : wv;
      float v = src[lane];
      float mx = wmax64(v);
      float e = expf(v - mx);
      float s = wred(e);
      dst[lane] = e / s;
    }
    __syncthreads();
    float os0 = 0.f, os1 = 0.f;
#pragma unroll 4
    for (int r = 0; r < NREG; ++r) {
      float rv = Rb[(size_t)r * DD + tid];
      os0 += at0[r] * rv; os1 += at1[r] * rv;
    }
    {
      float s0 = wred(os0), qq0 = wred(os0 * os0);
      float s1 = wred(os1), qq1 = wred(os1 * os1);
      if (lane == 0) { red[w*4] = s0; red[w*4+1] = qq0; red[w*4+2] = s1; red[w*4+3] = qq1; }
      __syncthreads();
      float S0 = 0, Q0 = 0, S1 = 0, Q1 = 0;
#pragma unroll
      for (int i = 0; i < 16; ++i) { S0 += red[i*4]; Q0 += red[i*4+1]; S1 += red[i*4+2]; Q1 += red[i*4+3]; }
      float m0 = S0 / DD, v0 = fmaxf(Q0 / DD - m0 * m0, 0.f);
      float m1 = S1 / DD, v1 = fmaxf(Q1 / DD - m1 * m1, 0.f);
      xn0[tid] = (os0 - m0) * rsqrtf(v0 + EPS) * ln1_g[tid] + ln1_b[tid];
      xn1[tid] = (os1 - m1) * rsqrtf(v1 + EPS) * ln2_g[tid] + ln2_b[tid];
      __syncthreads();
    }
    float p1v = b1[tid], p2v = b2[tid];
    {
      const float* c1 = w1 + tid;
      const float* c2 = w2 + tid;
#pragma unroll 4
      for (int d = 0; d < DD; ++d) {
        p1v += xn0[d] * c1[(size_t)d * FF];
        p2v += xn1[d] * c2[(size_t)d * FF];
      }
    }
    {
      int mmm = lane & 15, basel = lane & ~15;
      float mx1 = p1v, mx2 = p2v;
      for (int msk = 1; msk < 16; msk <<= 1) {
        mx1 = fmaxf(mx1, __shfl_xor(mx1, msk));
        mx2 = fmaxf(mx2, __shfl_xor(mx2, msk));
      }
      float e1 = expf(p1v - mx1), e2 = expf(p2v - mx2);
      float s1 = e1, s2 = e2;
      for (int msk = 1; msk < 16; msk <<= 1) { s1 += __shfl_xor(s1, msk); s2 += __shfl_xor(s2, msk); }
      float x = e1 / s1, y = e2 / s2;
      float addv = 0.f, subv = 0.f;
#pragma unroll
      for (int i = 0; i < 16; ++i) {
        float xi = __shfl(x, basel + i);
        float ya = __shfl(y, basel + ((mmm - i) & 15));
        float ys = __shfl(y, basel + ((i - mmm) & 15));
        addv += xi * ya; subv += xi * ys;
      }
      const float* pr = opcode_probs + ((size_t)b * LINES + t) * 2;
      mixs[tid] = pr[0] * addv + pr[1] * subv;
    }
    __syncthreads();
    float acc = b_res[tid];
    {
      const float* cr = w_res + tid;
#pragma unroll 4
      for (int f = 0; f < FF; ++f) acc += mixs[f] * cr[(size_t)f * DD];
    }
    {
      float s1 = wred(acc), s2 = wred(acc * acc);
      if (lane == 0) { red[w*2] = s1; red[w*2+1] = s2; }
      __syncthreads();
      float S = 0, Q = 0;
#pragma unroll
      for (int i = 0; i < 16; ++i) { S += red[i*2]; Q += red[i*2+1]; }
      float mn = S / DD, vr = fmaxf(Q / DD - mn * mn, 0.f);
      val[tid] = (acc - mn) * rsqrtf(vr + EPS) * lno_g[tid] + lno_b[tid];
      __syncthreads();
    }
    {
      float gt_ = gate[(size_t)b * LINES + t];
      float vv = val[tid];
#pragma unroll 4
      for (int r = 0; r < NREG; ++r) {
        float gg = gt_ * wv[r];
        size_t idx = (size_t)r * DD + tid;
        Rb[idx] = Rb[idx] * (1.f - gg) + gg * vv;
      }
    }
    __syncthreads();
  }
}

extern "C" void kernel_launch(void* const* d_in, const int* in_sizes, int n_in,
                              void* d_out, int out_size, void* d_ws, size_t ws_size,
                              hipStream_t stream) {
  const float* opcode = (const float*)d_in[0];
  const float* registers = (const float*)d_in[1];
  const float* k_write = (const float*)d_in[2];
  const float* q_read = (const float*)d_in[3];
  const float* gate = (const float*)d_in[5];
  const float* ln1_g = (const float*)d_in[6];
  const float* ln1_b = (const float*)d_in[7];
  const float* w1 = (const float*)d_in[8];
  const float* b1 = (const float*)d_in[9];
  const float* ln2_g = (const float*)d_in[10];
  const float* ln2_b = (const float*)d_in[11];
  const float* w2 = (const float*)d_in[12];
  const float* b2 = (const float*)d_in[13];
  const float* w_res = (const float*)d_in[14];
  const float* b_res = (const float*)d_in[15];
  const float* lno_g = (const float*)d_in[16];
  const float* lno_b = (const float*)d_in[17];
  float* R = (float*)d_out;

  if (ws_size >= (size_t)WS_NEED) {
    transcvt<<<dim3(16, 16, 3), 256, 0, stream>>>(w1, w2, w_res, (bf16_t*)d_ws);
    hipMemsetAsync((char*)d_ws + WS_CTR, 0, 1024, stream);
    interp3<<<BB, 1024, 0, stream>>>(opcode, registers, k_write, q_read, gate,
                                     ln1_g, ln1_b, b1, ln2_g, ln2_b, b2,
                                     b_res, lno_g, lno_b, (char*)d_ws, R);
  } else {
    hipMemcpyAsync(R, registers, (size_t)BB * NREG * DD * sizeof(float),
                   hipMemcpyDeviceToDevice, stream);
    interp_fb<<<BB, 1024, 0, stream>>>(opcode, k_write, q_read, gate, ln1_g, ln1_b,
                                       w1, b1, ln2_g, ln2_b, w2, b2, w_res, b_res,
                                       lno_g, lno_b, R);
  }
}